// Round 8
// baseline (222.100 us; speedup 1.0000x reference)
//
#include <hip/hip_runtime.h>

#define Bn 256
#define Nn 64
#define Tn 50
#define Fn 2
#define En 64
#define Hn 128
#define Rn 30
#define G4 512

typedef _Float16 h2    __attribute__((ext_vector_type(2)));
typedef _Float16 f16x8 __attribute__((ext_vector_type(8)));
typedef float    f32x4 __attribute__((ext_vector_type(4)));

__device__ __forceinline__ float sigf(float x) {
    return __builtin_amdgcn_rcpf(1.0f + __expf(-x));
}
__device__ __forceinline__ float tanh_fast(float x) {
    return 1.0f - 2.0f * __builtin_amdgcn_rcpf(__expf(2.0f * x) + 1.0f);
}
__device__ __forceinline__ float dot2(h2 a, h2 b, float c) {
#if __has_builtin(__builtin_amdgcn_fdot2)
    return __builtin_amdgcn_fdot2(a, b, c, false);
#else
    return fmaf((float)a[0], (float)b[0], fmaf((float)a[1], (float)b[1], c));
#endif
}
__device__ __forceinline__ h2 pack2(float a, float b) {
    h2 r; r[0] = (_Float16)a; r[1] = (_Float16)b; return r;
}
__device__ __forceinline__ h2 bch2(float u) { return __builtin_bit_cast(h2, u); }

// ---------------- k_pre: GCN+emb (node 0) fused with XI = emb @ W_ih_e + b_e ----------------
// (unchanged from R7 — verified correct)
__global__ __launch_bounds__(512) void k_pre(const float* __restrict__ src,
                                             const float* __restrict__ W_res,
                                             const float* __restrict__ W_gcn,
                                             const float* __restrict__ b_gcn,
                                             const float* __restrict__ W_ih_e,
                                             const float* __restrict__ b_e,
                                             _Float16* __restrict__ XI)
{
    const int tid  = threadIdx.x;
    const int lane = tid & 63;
    const int wv   = tid >> 6;
    const int task0 = blockIdx.x * 64;

    __shared__ __align__(16) _Float16 elds[64][64];
    __shared__ float2 xs[8][Nn];

    const float wg0 = W_gcn[lane], wg1 = W_gcn[En + lane];
    const float wr0 = W_res[lane], wr1 = W_res[En + lane];
    const float bg  = b_gcn[lane];

    for (int it = 0; it < 8; it++) {
        const int task = task0 + (wv << 3) + it;
        const int b = task / Tn;
        const int t = task - b * Tn;

        const float2 xv = *reinterpret_cast<const float2*>(
            src + (((size_t)b * Nn + lane) * Tn + t) * Fn);
        const float x0 = xv.x, x1 = xv.y;
        xs[wv][lane] = xv;

        float rowsum = 0.0f, w0 = 0.0f;
        #pragma unroll
        for (int k = 0; k < Nn; k++) {
            const float2 o = xs[wv][k];
            const float dx = x0 - o.x, dy = x1 - o.y;
            const float w = fminf(__builtin_amdgcn_rsqf(dx * dx + dy * dy), 1.0f);
            rowsum += w;
            if (k == 0) w0 = w;
        }
        const float dinv  = __builtin_amdgcn_rsqf(rowsum);
        const float dinv0 = __shfl(dinv, 0);
        const float a = w0 * dinv0 * dinv;

        float p0 = a * x0, p1 = a * x1;
        #pragma unroll
        for (int off = 32; off; off >>= 1) {
            p0 += __shfl_xor(p0, off);
            p1 += __shfl_xor(p1, off);
        }
        const float xa = __shfl(x0, 0);
        const float xb = __shfl(x1, 0);

        const float v = p0 * wg0 + p1 * wg1 + bg + xa * wr0 + xb * wr1;
        elds[(wv << 3) + it][lane] = (_Float16)fmaxf(v, 0.0f);
    }

    h2 wih[32];
    #pragma unroll
    for (int q = 0; q < 32; q++)
        wih[q] = pack2(W_ih_e[(size_t)(2 * q) * G4 + tid],
                       W_ih_e[(size_t)(2 * q + 1) * G4 + tid]);
    const float be = b_e[tid];
    __syncthreads();

    for (int it = 0; it < 64; it++) {
        const float4* e4 = reinterpret_cast<const float4*>(&elds[it][0]);
        float acc = be;
        #pragma unroll
        for (int q = 0; q < 8; q++) {
            const float4 u = e4[q];
            acc = dot2(wih[4 * q + 0], bch2(u.x), acc);
            acc = dot2(wih[4 * q + 1], bch2(u.y), acc);
            acc = dot2(wih[4 * q + 2], bch2(u.z), acc);
            acc = dot2(wih[4 * q + 3], bch2(u.w), acc);
        }
        XI[(size_t)(task0 + it) * G4 + tid] = (_Float16)acc;
    }
}

// ---------------- k_seq: MFMA-based encoder+decoder LSTM ----------------
// 16 blocks x 512 threads; block owns batches [16g, 16g+16) as MFMA M-dim.
// Wave wv owns N-columns [64wv, 64wv+64). W_hh fragments: 64 VGPRs/thread,
// loaded once per phase. Per step: 4 swizzled A-reads (h) + 16 MFMA +
// 4 b128 G-writes -> barrier -> 512-thread gate phase (4 cells each, c in
// regs, XI/bias added here) -> barrier. ~16 wave-instructions of math vs
// ~100 in the R7 dot2 structure = much shorter per-step critical path.
__global__ __launch_bounds__(512) void k_seq(
    const _Float16* __restrict__ XI,
    const float* __restrict__ src,
    const float* __restrict__ W_hh_e,
    const float* __restrict__ W1,     const float* __restrict__ b1,
    const float* __restrict__ W_ih_d, const float* __restrict__ W_hh_d,
    const float* __restrict__ b_d,
    const float* __restrict__ W2,     const float* __restrict__ b2,
    float* __restrict__ out)
{
    const int tid  = threadIdx.x;
    const int lane = tid & 63;
    const int wv   = tid >> 6;          // 0..7 : N-slice [64wv, 64wv+64)
    const int l15  = lane & 15;
    const int lg   = lane >> 4;         // 0..3 : k-subgroup / m-subgroup
    const int colB = wv * 64;
    const int bq0  = blockIdx.x * 16;

    // gate-phase mapping
    const int jj = tid & 127;           // cell column 0..127
    const int mg = tid >> 7;            // 0..3 : m-group (m = 4*mg+i)

    __shared__ __align__(16) _Float16 h_lds[16 * 128];        // 4 KB  (swizzled)
    __shared__ __align__(16) _Float16 ed_lds[16 * 64];        // 2 KB  (swizzled)
    __shared__ __align__(16) float    g_lds[G4 * 20];         // 40 KB [col][20] padded
    __shared__ __align__(16) _Float16 wi_frag[8 * 8 * 64 * 8];// 64 KB W_ih_d fragments
    __shared__ __align__(16) float    redw[8][8];

    char* hbase = reinterpret_cast<char*>(h_lds);
    char* ebase = reinterpret_cast<char*>(ed_lds);

    // ---- W_hh fragments into registers (encoder first) ----
    f16x8 bfr[4][4];   // [n][kt] : lane j holds W[kt*32+lg*8+j][colB+n*16+l15]
    {
        const float* W = W_hh_e;
        #pragma unroll
        for (int n = 0; n < 4; n++)
            #pragma unroll
            for (int kt = 0; kt < 4; kt++) {
                f16x8 v;
                #pragma unroll
                for (int j = 0; j < 8; j++) {
                    const int k = kt * 32 + lg * 8 + j;
                    v[j] = (_Float16)W[(size_t)k * G4 + colB + n * 16 + l15];
                }
                bfr[n][kt] = v;
            }
    }

    // zero h_lds (zeros are swizzle-invariant)
    #pragma unroll
    for (int idx = 0; idx < 2; idx++)
        reinterpret_cast<float*>(h_lds)[tid + idx * 512] = 0.0f;

    f32x4 cst = {};   // c-state for cells (4*mg+i, jj)
    const _Float16* XIb = XI + ((size_t)(bq0 + 4 * mg) * Tn) * G4 + jj;
    __syncthreads();

    // ---- encoder: 50 steps, 2 barriers/step ----
    for (int t = 0; t < Tn; t++) {
        // XI prefetch (consumed after barrier -> latency hidden by MFMA phase)
        _Float16 xiv[4][4];
        #pragma unroll
        for (int i = 0; i < 4; i++)
            #pragma unroll
            for (int g = 0; g < 4; g++)
                xiv[i][g] = XIb[((size_t)(i * Tn + t)) * G4 + g * 128];

        // A fragments from h_lds (swizzled, conflict-free)
        f16x8 af[4];
        #pragma unroll
        for (int kt = 0; kt < 4; kt++) {
            const int abyte = (((l15 * 128) + kt * 32 + lg * 8) * 2) ^ ((l15 & 7) << 4);
            af[kt] = *reinterpret_cast<const f16x8*>(hbase + abyte);
        }

        f32x4 acc[4] = {};
        #pragma unroll
        for (int kt = 0; kt < 4; kt++)
            #pragma unroll
            for (int n = 0; n < 4; n++)
                acc[n] = __builtin_amdgcn_mfma_f32_16x16x32_f16(af[kt], bfr[n][kt], acc[n], 0, 0, 0);

        #pragma unroll
        for (int n = 0; n < 4; n++)
            *reinterpret_cast<f32x4*>(&g_lds[(colB + n * 16 + l15) * 20 + lg * 4]) = acc[n];
        __syncthreads();

        // gate phase: thread owns cells (m = 4*mg+i, jj)
        f32x4 Gv[4];
        #pragma unroll
        for (int g = 0; g < 4; g++)
            Gv[g] = *reinterpret_cast<const f32x4*>(&g_lds[(g * 128 + jj) * 20 + 4 * mg]);

        #pragma unroll
        for (int i = 0; i < 4; i++) {
            const float gi = Gv[0][i] + (float)xiv[i][0];
            const float gf = Gv[1][i] + (float)xiv[i][1];
            const float gg = Gv[2][i] + (float)xiv[i][2];
            const float go = Gv[3][i] + (float)xiv[i][3];
            cst[i] = sigf(gf) * cst[i] + sigf(gi) * tanh_fast(gg);
            const float hv = sigf(go) * tanh_fast(cst[i]);
            const int m = 4 * mg + i;
            const int hbyte = (((m * 128) + jj) * 2) ^ ((m & 7) << 4);
            *reinterpret_cast<_Float16*>(hbase + hbyte) = (_Float16)hv;
        }
        __syncthreads();
    }

    // ---- decoder setup ----
    {   // W_hh_d fragments -> same registers
        const float* W = W_hh_d;
        #pragma unroll
        for (int n = 0; n < 4; n++)
            #pragma unroll
            for (int kt = 0; kt < 4; kt++) {
                f16x8 v;
                #pragma unroll
                for (int j = 0; j < 8; j++) {
                    const int k = kt * 32 + lg * 8 + j;
                    v[j] = (_Float16)W[(size_t)k * G4 + colB + n * 16 + l15];
                }
                bfr[n][kt] = v;
            }
    }
    // W_ih_d fragments -> LDS (pre-swizzled fragment order)
    #pragma unroll
    for (int f = 0; f < 8; f++) {       // f = n*2 + kt2
        const int n = f >> 1, kt2 = f & 1;
        f16x8 v;
        #pragma unroll
        for (int j = 0; j < 8; j++) {
            const int k = kt2 * 32 + lg * 8 + j;
            v[j] = (_Float16)W_ih_d[(size_t)k * G4 + colB + n * 16 + l15];
        }
        *reinterpret_cast<f16x8*>(&wi_frag[((wv * 8 + f) * 64 + lane) * 8]) = v;
    }

    // per-thread decoder constants
    const float bd0 = b_d[jj], bd1 = b_d[128 + jj], bd2 = b_d[256 + jj], bd3 = b_d[384 + jj];
    const float w2a = W2[jj * 2], w2b = W2[jj * 2 + 1];
    const int   e   = tid & 63;          // ED-phase mapping
    const int   mh  = tid >> 6;          // handles m = mh and mh+8
    const float w1a = W1[e], w1b = W1[En + e], b1v = b1[e];
    const float b20 = b2[0], b21 = b2[1];

    // init ED from xin = src[b, node 0, T-1, :]
    #pragma unroll
    for (int q = 0; q < 2; q++) {
        const int m = mh + 8 * q;
        const float xin0 = src[((size_t)(bq0 + m) * Nn * Tn + (Tn - 1)) * Fn + 0];
        const float xin1 = src[((size_t)(bq0 + m) * Nn * Tn + (Tn - 1)) * Fn + 1];
        const float ed = fmaxf(xin0 * w1a + xin1 * w1b + b1v, 0.0f);
        const int ebyte = (((m * 64) + e) * 2) ^ ((m & 7) << 4);
        *reinterpret_cast<_Float16*>(ebase + ebyte) = (_Float16)ed;
    }
    __syncthreads();

    // ---- decoder: 30 steps, 3 barriers/step ----
    for (int r = 0; r < Rn; r++) {
        f16x8 af[4];
        #pragma unroll
        for (int kt = 0; kt < 4; kt++) {
            const int abyte = (((l15 * 128) + kt * 32 + lg * 8) * 2) ^ ((l15 & 7) << 4);
            af[kt] = *reinterpret_cast<const f16x8*>(hbase + abyte);
        }
        f16x8 ae[2];
        #pragma unroll
        for (int kt2 = 0; kt2 < 2; kt2++) {
            const int aebyte = (((l15 * 64) + kt2 * 32 + lg * 8) * 2) ^ ((l15 & 7) << 4);
            ae[kt2] = *reinterpret_cast<const f16x8*>(ebase + aebyte);
        }

        f32x4 acc[4] = {};
        #pragma unroll
        for (int kt = 0; kt < 4; kt++)
            #pragma unroll
            for (int n = 0; n < 4; n++)
                acc[n] = __builtin_amdgcn_mfma_f32_16x16x32_f16(af[kt], bfr[n][kt], acc[n], 0, 0, 0);
        #pragma unroll
        for (int n = 0; n < 4; n++)
            #pragma unroll
            for (int kt2 = 0; kt2 < 2; kt2++) {
                const f16x8 bfe = *reinterpret_cast<const f16x8*>(
                    &wi_frag[((wv * 8 + n * 2 + kt2) * 64 + lane) * 8]);
                acc[n] = __builtin_amdgcn_mfma_f32_16x16x32_f16(ae[kt2], bfe, acc[n], 0, 0, 0);
            }

        #pragma unroll
        for (int n = 0; n < 4; n++)
            *reinterpret_cast<f32x4*>(&g_lds[(colB + n * 16 + l15) * 20 + lg * 4]) = acc[n];
        __syncthreads();

        // gates + h + out-projection partials
        f32x4 Gv[4];
        #pragma unroll
        for (int g = 0; g < 4; g++)
            Gv[g] = *reinterpret_cast<const f32x4*>(&g_lds[(g * 128 + jj) * 20 + 4 * mg]);

        float hv4[4];
        #pragma unroll
        for (int i = 0; i < 4; i++) {
            const float gi = Gv[0][i] + bd0;
            const float gf = Gv[1][i] + bd1;
            const float gg = Gv[2][i] + bd2;
            const float go = Gv[3][i] + bd3;
            cst[i] = sigf(gf) * cst[i] + sigf(gi) * tanh_fast(gg);
            const float hv = sigf(go) * tanh_fast(cst[i]);
            hv4[i] = hv;
            const int m = 4 * mg + i;
            const int hbyte = (((m * 128) + jj) * 2) ^ ((m & 7) << 4);
            *reinterpret_cast<_Float16*>(hbase + hbyte) = (_Float16)hv;
        }

        float p[8];
        #pragma unroll
        for (int i = 0; i < 4; i++) { p[2 * i] = hv4[i] * w2a; p[2 * i + 1] = hv4[i] * w2b; }
        #pragma unroll
        for (int off = 32; off; off >>= 1)
            #pragma unroll
            for (int v = 0; v < 8; v++) p[v] += __shfl_xor(p[v], off);
        if (lane == 0) {
            *reinterpret_cast<float4*>(&redw[wv][0]) = make_float4(p[0], p[1], p[2], p[3]);
            *reinterpret_cast<float4*>(&redw[wv][4]) = make_float4(p[4], p[5], p[6], p[7]);
        }
        __syncthreads();

        // out + next ED
        #pragma unroll
        for (int q = 0; q < 2; q++) {
            const int m = mh + 8 * q;
            const int mgq = m >> 2, idx = (m & 3) * 2;
            const float o0 = redw[2 * mgq][idx]     + redw[2 * mgq + 1][idx]     + b20;
            const float o1 = redw[2 * mgq][idx + 1] + redw[2 * mgq + 1][idx + 1] + b21;
            if (e < 2)
                out[(((size_t)(bq0 + m)) * Rn + r) * Fn + e] = e ? o1 : o0;
            if (r + 1 < Rn) {
                const float ed = fmaxf(o0 * w1a + o1 * w1b + b1v, 0.0f);
                const int ebyte = (((m * 64) + e) * 2) ^ ((m & 7) << 4);
                *reinterpret_cast<_Float16*>(ebase + ebyte) = (_Float16)ed;
            }
        }
        __syncthreads();
    }
}

extern "C" void kernel_launch(void* const* d_in, const int* in_sizes, int n_in,
                              void* d_out, int out_size, void* d_ws, size_t ws_size,
                              hipStream_t stream)
{
    const float* src    = (const float*)d_in[0];
    const float* W_res  = (const float*)d_in[2];
    const float* W_gcn  = (const float*)d_in[3];
    const float* b_gcn  = (const float*)d_in[4];
    const float* W_ih_e = (const float*)d_in[5];
    const float* W_hh_e = (const float*)d_in[6];
    const float* b_e    = (const float*)d_in[7];
    const float* W1     = (const float*)d_in[8];
    const float* b1     = (const float*)d_in[9];
    const float* W_ih_d = (const float*)d_in[10];
    const float* W_hh_d = (const float*)d_in[11];
    const float* b_d    = (const float*)d_in[12];
    const float* W2     = (const float*)d_in[13];
    const float* b2     = (const float*)d_in[14];

    float* out = (float*)d_out;
    _Float16* XI = (_Float16*)d_ws;   // 12800 x 512 fp16 = 13.1 MB scratch

    k_pre<<<(Bn * Tn) / 64, 512, 0, stream>>>(src, W_res, W_gcn, b_gcn, W_ih_e, b_e, XI);
    k_seq<<<Bn / 16, 512, 0, stream>>>(XI, src,
                                       W_hh_e,
                                       W1, b1,
                                       W_ih_d, W_hh_d, b_d,
                                       W2, b2, out);
}

// Round 9
// 158.494 us; speedup vs baseline: 1.4013x; 1.4013x over previous
//
#include <hip/hip_runtime.h>

#define Bn 256
#define Nn 64
#define Tn 50
#define Fn 2
#define En 64
#define Hn 128
#define Rn 30
#define G4 512

typedef _Float16 h2    __attribute__((ext_vector_type(2)));
typedef _Float16 f16x8 __attribute__((ext_vector_type(8)));
typedef float    f32x4 __attribute__((ext_vector_type(4)));

__device__ __forceinline__ float sigf(float x) {
    return __builtin_amdgcn_rcpf(1.0f + __expf(-x));
}
__device__ __forceinline__ float tanh_fast(float x) {
    return 1.0f - 2.0f * __builtin_amdgcn_rcpf(__expf(2.0f * x) + 1.0f);
}
__device__ __forceinline__ float dot2(h2 a, h2 b, float c) {
#if __has_builtin(__builtin_amdgcn_fdot2)
    return __builtin_amdgcn_fdot2(a, b, c, false);
#else
    return fmaf((float)a[0], (float)b[0], fmaf((float)a[1], (float)b[1], c));
#endif
}
__device__ __forceinline__ h2 pack2(float a, float b) {
    h2 r; r[0] = (_Float16)a; r[1] = (_Float16)b; return r;
}
__device__ __forceinline__ h2 bch2(float u)        { return __builtin_bit_cast(h2, u); }
__device__ __forceinline__ h2 bchu(unsigned int u) { return __builtin_bit_cast(h2, u); }

// ---------------- k_pre: GCN+emb (node 0) fused with XI = emb @ W_ih_e + b_e ----------------
// XI layout v2: XI[task][c*4 + g]  (c = cell 0..127, g = gate 0..3) so k_seq
// threads read their 4 gate biases as one dwordx2. Thread tid owns column
// colp = (tid&3)*128 + (tid>>2); its output lands at element tid -> coalesced.
__global__ __launch_bounds__(512) void k_pre(const float* __restrict__ src,
                                             const float* __restrict__ W_res,
                                             const float* __restrict__ W_gcn,
                                             const float* __restrict__ b_gcn,
                                             const float* __restrict__ W_ih_e,
                                             const float* __restrict__ b_e,
                                             _Float16* __restrict__ XI)
{
    const int tid  = threadIdx.x;
    const int lane = tid & 63;
    const int wv   = tid >> 6;
    const int task0 = blockIdx.x * 64;

    __shared__ __align__(16) _Float16 elds[64][64];
    __shared__ float2 xs[8][Nn];

    const float wg0 = W_gcn[lane], wg1 = W_gcn[En + lane];
    const float wr0 = W_res[lane], wr1 = W_res[En + lane];
    const float bg  = b_gcn[lane];

    for (int it = 0; it < 8; it++) {
        const int task = task0 + (wv << 3) + it;
        const int b = task / Tn;
        const int t = task - b * Tn;

        const float2 xv = *reinterpret_cast<const float2*>(
            src + (((size_t)b * Nn + lane) * Tn + t) * Fn);
        const float x0 = xv.x, x1 = xv.y;
        xs[wv][lane] = xv;

        float rowsum = 0.0f, w0 = 0.0f;
        #pragma unroll
        for (int k = 0; k < Nn; k++) {
            const float2 o = xs[wv][k];
            const float dx = x0 - o.x, dy = x1 - o.y;
            const float w = fminf(__builtin_amdgcn_rsqf(dx * dx + dy * dy), 1.0f);
            rowsum += w;
            if (k == 0) w0 = w;
        }
        const float dinv  = __builtin_amdgcn_rsqf(rowsum);
        const float dinv0 = __shfl(dinv, 0);
        const float a = w0 * dinv0 * dinv;

        float p0 = a * x0, p1 = a * x1;
        #pragma unroll
        for (int off = 32; off; off >>= 1) {
            p0 += __shfl_xor(p0, off);
            p1 += __shfl_xor(p1, off);
        }
        const float xa = __shfl(x0, 0);
        const float xb = __shfl(x1, 0);

        const float v = p0 * wg0 + p1 * wg1 + bg + xa * wr0 + xb * wr1;
        elds[(wv << 3) + it][lane] = (_Float16)fmaxf(v, 0.0f);
    }

    const int colp = (tid & 3) * 128 + (tid >> 2);   // gate (tid&3), cell (tid>>2)
    h2 wih[32];
    #pragma unroll
    for (int q = 0; q < 32; q++)
        wih[q] = pack2(W_ih_e[(size_t)(2 * q) * G4 + colp],
                       W_ih_e[(size_t)(2 * q + 1) * G4 + colp]);
    const float be = b_e[colp];
    __syncthreads();

    for (int it = 0; it < 64; it++) {
        const float4* e4 = reinterpret_cast<const float4*>(&elds[it][0]);
        float acc = be;
        #pragma unroll
        for (int q = 0; q < 8; q++) {
            const float4 u = e4[q];
            acc = dot2(wih[4 * q + 0], bch2(u.x), acc);
            acc = dot2(wih[4 * q + 1], bch2(u.y), acc);
            acc = dot2(wih[4 * q + 2], bch2(u.z), acc);
            acc = dot2(wih[4 * q + 3], bch2(u.w), acc);
        }
        XI[(size_t)(task0 + it) * G4 + tid] = (_Float16)acc;
    }
}

// ---------------- k_seq: MFMA LSTM, in-register gates, 1 barrier/enc step ----------------
// 16 blocks x 512 thr; block owns batches [16g,16g+16) (MFMA M). Wave wv owns
// cells [16wv,16wv+16): B-tiles at cols g*128+16wv+l15 for all 4 gates ->
// after MFMA each lane holds i,f,g,o for cells (m=4lg+i, c=16wv+l15) ->
// gates fully in-register (no g_lds round trip). XI prefetched 1 step ahead
// (4 dwordx2, coalesced). h double-buffered [m][128] fp16, XOR-swizzled.
__global__ __launch_bounds__(512) void k_seq(
    const _Float16* __restrict__ XI,
    const float* __restrict__ src,
    const float* __restrict__ W_hh_e,
    const float* __restrict__ W1,     const float* __restrict__ b1,
    const float* __restrict__ W_ih_d, const float* __restrict__ W_hh_d,
    const float* __restrict__ b_d,
    const float* __restrict__ W2,     const float* __restrict__ b2,
    float* __restrict__ out)
{
    const int tid  = threadIdx.x;
    const int lane = tid & 63;
    const int wv   = tid >> 6;          // 0..7
    const int l15  = lane & 15;
    const int lg   = lane >> 4;         // 0..3
    const int cc   = wv * 16 + l15;     // cell column 0..127
    const int bq0  = blockIdx.x * 16;

    __shared__ __align__(16) _Float16 h_lds[2][16 * 128];    // 8 KB, swizzled
    __shared__ __align__(16) _Float16 ed_lds[2][16 * 64];    // 4 KB, swizzled
    __shared__ __align__(16) _Float16 wi_frag[8 * 8 * 64 * 8]; // 64 KB
    __shared__ __align__(16) float    redw[8][4][8];          // 1 KB

    // ---- encoder W_hh fragments (64 VGPR) ----
    f16x8 bfr[4][4];   // [gate][kt]
    #pragma unroll
    for (int g = 0; g < 4; g++)
        #pragma unroll
        for (int kt = 0; kt < 4; kt++) {
            f16x8 v;
            #pragma unroll
            for (int j = 0; j < 8; j++)
                v[j] = (_Float16)W_hh_e[(size_t)(kt * 32 + lg * 8 + j) * G4 + g * 128 + cc];
            bfr[g][kt] = v;
        }

    // zero h buffer 0 (zeros are swizzle-invariant)
    #pragma unroll
    for (int q = 0; q < 2; q++)
        reinterpret_cast<float*>(&h_lds[0][0])[tid + q * 512] = 0.0f;

    f32x4 cst = {};
    char* const hb0 = reinterpret_cast<char*>(&h_lds[0][0]);
    char* const hb1 = reinterpret_cast<char*>(&h_lds[1][0]);

    // XI prefetch for t=0
    uint2 xiA[4];
    #pragma unroll
    for (int i = 0; i < 4; i++)
        xiA[i] = *reinterpret_cast<const uint2*>(
            XI + ((size_t)(bq0 + 4 * lg + i) * Tn) * G4 + cc * 4);
    __syncthreads();

    // ---- encoder: 50 steps, 1 barrier/step ----
    for (int t = 0; t < Tn; t++) {
        const int cur = t & 1;
        char* const hr = cur ? hb1 : hb0;
        char* const hw = cur ? hb0 : hb1;

        // prefetch XI for t+1 (consumed next iteration -> ~1 step of latency hiding)
        uint2 xiB[4];
        const int tn = (t + 1 < Tn) ? t + 1 : t;
        #pragma unroll
        for (int i = 0; i < 4; i++)
            xiB[i] = *reinterpret_cast<const uint2*>(
                XI + ((size_t)(bq0 + 4 * lg + i) * Tn + tn) * G4 + cc * 4);

        // A fragments (h) — swizzled b128, conflict-free
        f16x8 af[4];
        #pragma unroll
        for (int kt = 0; kt < 4; kt++) {
            const int abyte = (l15 * 256 + kt * 64 + lg * 16) ^ ((l15 & 7) << 4);
            af[kt] = *reinterpret_cast<const f16x8*>(hr + abyte);
        }

        f32x4 acc[4] = {};
        #pragma unroll
        for (int kt = 0; kt < 4; kt++)
            #pragma unroll
            for (int g = 0; g < 4; g++)
                acc[g] = __builtin_amdgcn_mfma_f32_16x16x32_f16(af[kt], bfr[g][kt], acc[g], 0, 0, 0);

        // in-register gates for cells (m = 4lg+i, c = cc)
        #pragma unroll
        for (int i = 0; i < 4; i++) {
            const h2 lo = bchu(xiA[i].x);
            const h2 hi = bchu(xiA[i].y);
            const float gi = acc[0][i] + (float)lo[0];
            const float gf = acc[1][i] + (float)lo[1];
            const float gg = acc[2][i] + (float)hi[0];
            const float go = acc[3][i] + (float)hi[1];
            cst[i] = sigf(gf) * cst[i] + sigf(gi) * tanh_fast(gg);
            const float hv = sigf(go) * tanh_fast(cst[i]);
            const int m = 4 * lg + i;
            const int hbyte = (m * 256 + cc * 2) ^ ((m & 7) << 4);
            *reinterpret_cast<_Float16*>(hw + hbyte) = (_Float16)hv;
        }
        #pragma unroll
        for (int i = 0; i < 4; i++) xiA[i] = xiB[i];
        __syncthreads();
    }

    // ---- decoder setup ----
    #pragma unroll
    for (int g = 0; g < 4; g++)
        #pragma unroll
        for (int kt = 0; kt < 4; kt++) {
            f16x8 v;
            #pragma unroll
            for (int j = 0; j < 8; j++)
                v[j] = (_Float16)W_hh_d[(size_t)(kt * 32 + lg * 8 + j) * G4 + g * 128 + cc];
            bfr[g][kt] = v;
        }
    #pragma unroll
    for (int g = 0; g < 4; g++)
        #pragma unroll
        for (int kt2 = 0; kt2 < 2; kt2++) {
            f16x8 v;
            #pragma unroll
            for (int j = 0; j < 8; j++)
                v[j] = (_Float16)W_ih_d[(size_t)(kt2 * 32 + lg * 8 + j) * G4 + g * 128 + cc];
            *reinterpret_cast<f16x8*>(&wi_frag[((wv * 8 + g * 2 + kt2) * 64 + lane) * 8]) = v;
        }

    const float bd0 = b_d[cc], bd1 = b_d[128 + cc], bd2 = b_d[256 + cc], bd3 = b_d[384 + cc];
    const float w2a = W2[cc * 2], w2b = W2[cc * 2 + 1];
    const int   e   = tid & 63;
    const int   mh  = wv;                // handles m = mh, mh+8
    const float w1a = W1[e], w1b = W1[En + e], b1v = b1[e];
    const float b20 = b2[0], b21 = b2[1];

    char* const eb0 = reinterpret_cast<char*>(&ed_lds[0][0]);
    char* const eb1 = reinterpret_cast<char*>(&ed_lds[1][0]);

    // ED init from xin = src[b, node0, T-1, :]
    #pragma unroll
    for (int q = 0; q < 2; q++) {
        const int m = mh + 8 * q;
        const float xin0 = src[((size_t)(bq0 + m) * Nn * Tn + (Tn - 1)) * Fn + 0];
        const float xin1 = src[((size_t)(bq0 + m) * Nn * Tn + (Tn - 1)) * Fn + 1];
        const float ed = fmaxf(xin0 * w1a + xin1 * w1b + b1v, 0.0f);
        const int ebyte = (m * 128 + e * 2) ^ ((m & 7) << 4);
        *reinterpret_cast<_Float16*>(eb0 + ebyte) = (_Float16)ed;
    }
    __syncthreads();

    // ---- decoder: 30 steps, 2 barriers/step ----
    for (int r = 0; r < Rn; r++) {
        const int cur = r & 1;
        char* const hr = cur ? hb1 : hb0;
        char* const hw = cur ? hb0 : hb1;
        char* const er = cur ? eb1 : eb0;
        char* const ew = cur ? eb0 : eb1;

        f16x8 af[4];
        #pragma unroll
        for (int kt = 0; kt < 4; kt++) {
            const int abyte = (l15 * 256 + kt * 64 + lg * 16) ^ ((l15 & 7) << 4);
            af[kt] = *reinterpret_cast<const f16x8*>(hr + abyte);
        }
        f16x8 ae[2];
        #pragma unroll
        for (int kt2 = 0; kt2 < 2; kt2++) {
            const int aebyte = (l15 * 128 + kt2 * 64 + lg * 16) ^ ((l15 & 7) << 4);
            ae[kt2] = *reinterpret_cast<const f16x8*>(er + aebyte);
        }

        f32x4 acc[4] = {};
        #pragma unroll
        for (int kt = 0; kt < 4; kt++)
            #pragma unroll
            for (int g = 0; g < 4; g++)
                acc[g] = __builtin_amdgcn_mfma_f32_16x16x32_f16(af[kt], bfr[g][kt], acc[g], 0, 0, 0);
        #pragma unroll
        for (int g = 0; g < 4; g++)
            #pragma unroll
            for (int kt2 = 0; kt2 < 2; kt2++) {
                const f16x8 bfe = *reinterpret_cast<const f16x8*>(
                    &wi_frag[((wv * 8 + g * 2 + kt2) * 64 + lane) * 8]);
                acc[g] = __builtin_amdgcn_mfma_f32_16x16x32_f16(ae[kt2], bfe, acc[g], 0, 0, 0);
            }

        float hv4[4];
        #pragma unroll
        for (int i = 0; i < 4; i++) {
            const float gi = acc[0][i] + bd0;
            const float gf = acc[1][i] + bd1;
            const float gg = acc[2][i] + bd2;
            const float go = acc[3][i] + bd3;
            cst[i] = sigf(gf) * cst[i] + sigf(gi) * tanh_fast(gg);
            const float hv = sigf(go) * tanh_fast(cst[i]);
            hv4[i] = hv;
            const int m = 4 * lg + i;
            const int hbyte = (m * 256 + cc * 2) ^ ((m & 7) << 4);
            *reinterpret_cast<_Float16*>(hw + hbyte) = (_Float16)hv;
        }

        // out-projection partials: butterfly over the 16 cells of this wave
        float p[8];
        #pragma unroll
        for (int i = 0; i < 4; i++) { p[2 * i] = hv4[i] * w2a; p[2 * i + 1] = hv4[i] * w2b; }
        #pragma unroll
        for (int off = 1; off < 16; off <<= 1)
            #pragma unroll
            for (int v = 0; v < 8; v++) p[v] += __shfl_xor(p[v], off);
        if (l15 == 0) {
            *reinterpret_cast<float4*>(&redw[wv][lg][0]) = make_float4(p[0], p[1], p[2], p[3]);
            *reinterpret_cast<float4*>(&redw[wv][lg][4]) = make_float4(p[4], p[5], p[6], p[7]);
        }
        __syncthreads();

        // o, out-write, next ED (broadcast redw reads; m uniform per wave)
        #pragma unroll
        for (int q = 0; q < 2; q++) {
            const int m = mh + 8 * q;
            const int lgq = m >> 2, iq = m & 3;
            float o0 = b20, o1 = b21;
            #pragma unroll
            for (int w8 = 0; w8 < 8; w8++) {
                o0 += redw[w8][lgq][iq * 2];
                o1 += redw[w8][lgq][iq * 2 + 1];
            }
            if (e < 2)
                out[(((size_t)(bq0 + m)) * Rn + r) * Fn + e] = e ? o1 : o0;
            if (r + 1 < Rn) {
                const float ed = fmaxf(o0 * w1a + o1 * w1b + b1v, 0.0f);
                const int ebyte = (m * 128 + e * 2) ^ ((m & 7) << 4);
                *reinterpret_cast<_Float16*>(ew + ebyte) = (_Float16)ed;
            }
        }
        __syncthreads();
    }
}

extern "C" void kernel_launch(void* const* d_in, const int* in_sizes, int n_in,
                              void* d_out, int out_size, void* d_ws, size_t ws_size,
                              hipStream_t stream)
{
    const float* src    = (const float*)d_in[0];
    const float* W_res  = (const float*)d_in[2];
    const float* W_gcn  = (const float*)d_in[3];
    const float* b_gcn  = (const float*)d_in[4];
    const float* W_ih_e = (const float*)d_in[5];
    const float* W_hh_e = (const float*)d_in[6];
    const float* b_e    = (const float*)d_in[7];
    const float* W1     = (const float*)d_in[8];
    const float* b1     = (const float*)d_in[9];
    const float* W_ih_d = (const float*)d_in[10];
    const float* W_hh_d = (const float*)d_in[11];
    const float* b_d    = (const float*)d_in[12];
    const float* W2     = (const float*)d_in[13];
    const float* b2     = (const float*)d_in[14];

    float* out = (float*)d_out;
    _Float16* XI = (_Float16*)d_ws;   // 12800 x 512 fp16 = 13.1 MB scratch

    k_pre<<<(Bn * Tn) / 64, 512, 0, stream>>>(src, W_res, W_gcn, b_gcn, W_ih_e, b_e, XI);
    k_seq<<<Bn / 16, 512, 0, stream>>>(XI, src,
                                       W_hh_e,
                                       W1, b1,
                                       W_ih_d, W_hh_d, b_d,
                                       W2, b2, out);
}